// Round 5
// baseline (205.508 us; speedup 1.0000x reference)
//
#include <hip/hip_runtime.h>

#define B_ 2048
#define N_ 200
#define D_ 128
#define NE1 4   // NE+1
#define NN1 3   // NN+1

// ---------------------------------------------------------------------------
// Mask storage detection (bool-bytes vs int32). Flag -> ws[0].
// ---------------------------------------------------------------------------
__global__ void detect_mask_kernel(const unsigned int* __restrict__ mw,
                                   int nwords, unsigned int* __restrict__ flag) {
  __shared__ int sbad;
  if (threadIdx.x == 0) sbad = 0;
  __syncthreads();
  int bad = 0;
  for (int i = blockIdx.x * blockDim.x + threadIdx.x; i < nwords;
       i += gridDim.x * blockDim.x)
    if (mw[i] > 1u) bad = 1;
  if (bad) sbad = 1;
  __syncthreads();
  if (threadIdx.x == 0 && sbad) atomicOr(flag, 1u);
}

// ---------------------------------------------------------------------------
// Prep: qM[b, e*4+h, d] = pri[h,u_b,e]/sqrt(32) * sum_i (Wq[e]q_b)[h*32+i] * Wk[e][h*32+i][d]
// One block per (e, 16-b tile). Weights amortized over 16 b.
// ---------------------------------------------------------------------------
__global__ __launch_bounds__(256) void prep_kernel(
    const float* __restrict__ q, const float* __restrict__ Wq,
    const float* __restrict__ Wk, const float* __restrict__ rel_pri,
    const int* __restrict__ utype, float* __restrict__ qM) {
  const int e = blockIdx.x & 3;
  const int b0 = (blockIdx.x >> 2) * 16;
  const int tid = threadIdx.x;

  __shared__ float q_s[16][132];
  __shared__ float Qe_s[16][132];
  __shared__ float pri_s[16][4];
  __shared__ int u_s[16];

  for (int idx = tid; idx < 16 * 32; idx += 256) {
    int r = idx >> 5, c = idx & 31;
    ((float4*)&q_s[r][0])[c] = ((const float4*)(q + (size_t)(b0 + r) * 128))[c];
  }
  if (tid < 16) u_s[tid] = utype[b0 + tid];
  __syncthreads();

  if (tid < 64) {
    int bl = tid >> 2, h = tid & 3;
    pri_s[bl][h] =
        rel_pri[(h * NN1 + u_s[bl]) * NE1 + e] * 0.17677669529663687f;
  }

  // Step A: Qe_s[b][j] = Wq[e][j][:] . q[b]
  {
    const int j = tid & 127, half = tid >> 7;
    float acc[8] = {0, 0, 0, 0, 0, 0, 0, 0};
    const float4* wq = (const float4*)(Wq + ((size_t)e * 128 + j) * 128);
    for (int c = 0; c < 32; ++c) {
      float4 w = wq[c];
#pragma unroll
      for (int bg = 0; bg < 8; ++bg) {
        float4 qq = ((const float4*)&q_s[half * 8 + bg][0])[c];
        acc[bg] += w.x * qq.x + w.y * qq.y + w.z * qq.z + w.w * qq.w;
      }
    }
#pragma unroll
    for (int bg = 0; bg < 8; ++bg) Qe_s[half * 8 + bg][j] = acc[bg];
  }
  __syncthreads();

  // Step B: qM[b, e*4+h, d] = sum_i Qe_s[b][h*32+i] * Wk[e][h*32+i][d]
  {
    const int d = tid & 127, half = tid >> 7;
    for (int h = 0; h < 4; ++h) {
      float acc[8] = {0, 0, 0, 0, 0, 0, 0, 0};
#pragma unroll
      for (int i4 = 0; i4 < 8; ++i4) {
        const float* wkp = Wk + ((size_t)e * 128 + h * 32 + i4 * 4) * 128 + d;
        float w0 = wkp[0], w1 = wkp[128], w2 = wkp[256], w3 = wkp[384];
#pragma unroll
        for (int bg = 0; bg < 8; ++bg) {
          float4 qe = ((const float4*)&Qe_s[half * 8 + bg][0])[h * 8 + i4];
          acc[bg] = fmaf(qe.x, w0, acc[bg]);
          acc[bg] = fmaf(qe.y, w1, acc[bg]);
          acc[bg] = fmaf(qe.z, w2, acc[bg]);
          acc[bg] = fmaf(qe.w, w3, acc[bg]);
        }
      }
#pragma unroll
      for (int bg = 0; bg < 8; ++bg) {
        int bl = half * 8 + bg;
        qM[((size_t)(b0 + bl) * 16 + e * 4 + h) * 128 + d] =
            acc[bg] * pri_s[bl][h];
      }
    }
  }
}

// ---------------------------------------------------------------------------
// Stream: logits + softmax + PV + Wv + FC + LN. One block per b, ~14 KB LDS.
// ---------------------------------------------------------------------------
__global__ __launch_bounds__(256, 8) void stream_kernel(
    const float* __restrict__ qM, const float* __restrict__ k,
    const float* __restrict__ v, const float* __restrict__ Wv,
    const float* __restrict__ W_fc, const float* __restrict__ b_fc,
    const float* __restrict__ ln_gamma, const float* __restrict__ ln_beta,
    const float* __restrict__ q, const int* __restrict__ etype,
    const int* __restrict__ utype, const void* __restrict__ maskp,
    const unsigned int* __restrict__ flag, float* __restrict__ y_out,
    float* __restrict__ attn_out) {
  const int b = blockIdx.x, tid = threadIdx.x;
  const int g = tid & 3, grp = tid >> 2;

  __shared__ float qm_s[16][132];  // qM rows; reused for s[h][e][:] after PV
  __shared__ float p_s[4][200];    // logits -> probs; later FC partials
  __shared__ float msel[200];
  __shared__ int et_s[200];
  __shared__ float q_s[128];
  __shared__ float part_s[128];
  __shared__ float red_s[8];
  __shared__ int u_s;

  // ---------------- metadata + qM load ----------------
  if (tid == 0) u_s = utype[b];
  if (tid < 128) q_s[tid] = q[(size_t)b * D_ + tid];
  const unsigned int isBool = flag[0];
  for (int i = tid; i < N_; i += 256) {
    et_s[i] = etype[(size_t)b * N_ + i];
    int m;
    if (isBool)
      m = ((const unsigned char*)maskp)[(size_t)b * N_ + i];
    else
      m = ((const int*)maskp)[(size_t)b * N_ + i];
    msel[i] = m ? 1.f : 0.f;
  }
  {
    const float4* qsrc = (const float4*)(qM + (size_t)b * 2048);
    for (int idx = tid; idx < 512; idx += 256) {
      int r = idx >> 5, c = idx & 31;
      ((float4*)&qm_s[r][0])[c] = qsrc[idx];
    }
  }
  __syncthreads();

  // ---------------- logits: 4 lanes per n, 8 loads in flight ----------------
#pragma unroll
  for (int pass = 0; pass < 4; ++pass) {
    int n = pass * 64 + grp;
    if (n < N_) {
      const float4* kr = (const float4*)(k + ((size_t)b * N_ + n) * D_);
      float4 kb[8];
#pragma unroll
      for (int t = 0; t < 8; ++t) kb[t] = kr[g + 4 * t];
      const int eh0 = et_s[n] * 4;
      const float4* m0 = (const float4*)&qm_s[eh0 + 0][0];
      const float4* m1 = (const float4*)&qm_s[eh0 + 1][0];
      const float4* m2 = (const float4*)&qm_s[eh0 + 2][0];
      const float4* m3 = (const float4*)&qm_s[eh0 + 3][0];
      float a0 = 0.f, a1 = 0.f, a2 = 0.f, a3 = 0.f;
#pragma unroll
      for (int t = 0; t < 8; ++t) {
        int c = g + 4 * t;
        float4 x0 = m0[c];
        a0 += kb[t].x * x0.x + kb[t].y * x0.y + kb[t].z * x0.z + kb[t].w * x0.w;
        float4 x1 = m1[c];
        a1 += kb[t].x * x1.x + kb[t].y * x1.y + kb[t].z * x1.z + kb[t].w * x1.w;
        float4 x2 = m2[c];
        a2 += kb[t].x * x2.x + kb[t].y * x2.y + kb[t].z * x2.z + kb[t].w * x2.w;
        float4 x3 = m3[c];
        a3 += kb[t].x * x3.x + kb[t].y * x3.y + kb[t].z * x3.z + kb[t].w * x3.w;
      }
      a0 += __shfl_xor(a0, 1);
      a0 += __shfl_xor(a0, 2);
      a1 += __shfl_xor(a1, 1);
      a1 += __shfl_xor(a1, 2);
      a2 += __shfl_xor(a2, 1);
      a2 += __shfl_xor(a2, 2);
      a3 += __shfl_xor(a3, 1);
      a3 += __shfl_xor(a3, 2);
      if (g == 0) {
        bool m = msel[n] > 0.5f;
        p_s[0][n] = m ? -1e10f : a0;
        p_s[1][n] = m ? -1e10f : a1;
        p_s[2][n] = m ? -1e10f : a2;
        p_s[3][n] = m ? -1e10f : a3;
      }
    }
  }
  __syncthreads();

  // ---------------- softmax (one wave per head) + attn write ----------------
  {
    const int w = tid >> 6, l = tid & 63;
    float mx = -1e30f;
    for (int n = l; n < N_; n += 64) mx = fmaxf(mx, p_s[w][n]);
#pragma unroll
    for (int o = 32; o; o >>= 1) mx = fmaxf(mx, __shfl_xor(mx, o));
    float sum = 0.f;
    for (int n = l; n < N_; n += 64) {
      float e = __expf(p_s[w][n] - mx);
      p_s[w][n] = e;
      sum += e;
    }
#pragma unroll
    for (int o = 32; o; o >>= 1) sum += __shfl_xor(sum, o);
    float inv = 1.f / sum;
    for (int n = l; n < N_; n += 64) {
      float pp = p_s[w][n] * inv;
      p_s[w][n] = pp;
      attn_out[((size_t)w * B_ + b) * N_ + n] = pp;
    }
  }
  __syncthreads();

  // ---------------- PV: s[h][e][d], float2 v loads, 4-deep ----------------
  {
    const int h = tid >> 6, l = tid & 63;
    float a0[4] = {0.f, 0.f, 0.f, 0.f}, a1[4] = {0.f, 0.f, 0.f, 0.f};
    const float2* vb2 = (const float2*)(v + (size_t)b * N_ * D_);
    for (int n = 0; n < N_; n += 4) {
      float2 vv[4];
      float pv[4];
      int en[4];
#pragma unroll
      for (int u = 0; u < 4; ++u) vv[u] = vb2[(n + u) * 64 + l];
#pragma unroll
      for (int u = 0; u < 4; ++u) {
        pv[u] = p_s[h][n + u];
        en[u] = et_s[n + u];
      }
#pragma unroll
      for (int u = 0; u < 4; ++u) {
#pragma unroll
        for (int e = 0; e < 4; ++e) {
          float sel = (en[u] == e) ? pv[u] : 0.f;
          a0[e] = fmaf(sel, vv[u].x, a0[e]);
          a1[e] = fmaf(sel, vv[u].y, a1[e]);
        }
      }
    }
    __syncthreads();  // done reading qm_s as qM
#pragma unroll
    for (int e = 0; e < 4; ++e) {
      qm_s[e * 4 + h][2 * l] = a0[e];
      qm_s[e * 4 + h][2 * l + 1] = a1[e];
    }
  }
  __syncthreads();

  // ---------------- Wv contract: 4 lanes per row, 8 loads in flight ----------------
  {
#pragma unroll
    for (int pass = 0; pass < 2; ++pass) {
      int row = pass * 64 + grp;
      int hh = row >> 5;
      float acc = 0.f;
#pragma unroll
      for (int e = 0; e < 4; ++e) {
        const float4* wr = (const float4*)(Wv + ((size_t)e * 128 + row) * 128);
        const float4* ss = (const float4*)&qm_s[e * 4 + hh][0];
        float4 wb[8];
#pragma unroll
        for (int t = 0; t < 8; ++t) wb[t] = wr[g + 4 * t];
#pragma unroll
        for (int t = 0; t < 8; ++t) {
          float4 sv = ss[g + 4 * t];
          acc += wb[t].x * sv.x + wb[t].y * sv.y + wb[t].z * sv.z +
                 wb[t].w * sv.w;
        }
      }
      acc += __shfl_xor(acc, 1);
      acc += __shfl_xor(acc, 2);
      if (g == 0) part_s[row] = acc;
    }
  }
  __syncthreads();

  // ---------------- FC (r-split) + residual + LN ----------------
  {
    const int j = tid & 127, halfR = tid >> 7;
    const float* wf = W_fc + ((size_t)u_s * 128 + halfR * 64) * 128 + j;
    float acc = 0.f;
    for (int r0 = 0; r0 < 64; r0 += 8) {
      float wv[8], ov[8];
#pragma unroll
      for (int u = 0; u < 8; ++u) wv[u] = wf[(r0 + u) * 128];
#pragma unroll
      for (int u = 0; u < 8; ++u) ov[u] = part_s[halfR * 64 + r0 + u];
#pragma unroll
      for (int u = 0; u < 8; ++u) acc = fmaf(ov[u], wv[u], acc);
    }
    ((float*)p_s)[tid] = acc;
  }
  __syncthreads();

  float x = 0.f;
  if (tid < 128) {
    x = ((float*)p_s)[tid] + ((float*)p_s)[128 + tid] + b_fc[u_s * 128 + tid] +
        q_s[tid];
  }
  float s1 = (tid < 128) ? x : 0.f, s2 = (tid < 128) ? x * x : 0.f;
#pragma unroll
  for (int o = 32; o; o >>= 1) {
    s1 += __shfl_xor(s1, o);
    s2 += __shfl_xor(s2, o);
  }
  if (tid < 128 && (tid & 63) == 0) {
    red_s[tid >> 6] = s1;
    red_s[4 + (tid >> 6)] = s2;
  }
  __syncthreads();
  if (tid < 128) {
    float t1 = red_s[0] + red_s[1], t2 = red_s[4] + red_s[5];
    float mu = t1 * (1.f / 128.f);
    float var = t2 * (1.f / 128.f) - mu * mu;
    float yv = (x - mu) * rsqrtf(var + 1e-5f) * ln_gamma[tid] + ln_beta[tid];
    y_out[(size_t)b * 128 + tid] = yv;
  }
}

extern "C" void kernel_launch(void* const* d_in, const int* in_sizes, int n_in,
                              void* d_out, int out_size, void* d_ws,
                              size_t ws_size, hipStream_t stream) {
  const float* q = (const float*)d_in[0];
  const float* k = (const float*)d_in[1];
  const float* v = (const float*)d_in[2];
  const float* Wq = (const float*)d_in[3];
  const float* Wk = (const float*)d_in[4];
  const float* Wv = (const float*)d_in[5];
  const float* rp = (const float*)d_in[6];
  const float* Wf = (const float*)d_in[7];
  const float* bf = (const float*)d_in[8];
  const float* g = (const float*)d_in[9];
  const float* be = (const float*)d_in[10];
  const int* et = (const int*)d_in[11];
  const int* ut = (const int*)d_in[12];
  const void* mask = d_in[13];

  float* y = (float*)d_out;
  float* attn = y + (size_t)B_ * D_;
  unsigned int* flag = (unsigned int*)d_ws;
  float* qM = (float*)((char*)d_ws + 256);  // 2048*16*128 floats = 16.8 MB

  hipMemsetAsync(d_ws, 0, 4, stream);
  detect_mask_kernel<<<64, 256, 0, stream>>>((const unsigned int*)mask,
                                             B_ * N_ / 4, flag);
  prep_kernel<<<512, 256, 0, stream>>>(q, Wq, Wk, rp, ut, qM);
  stream_kernel<<<B_, 256, 0, stream>>>(qM, k, v, Wv, Wf, bf, g, be, q, et, ut,
                                        mask, flag, y, attn);
}

// Round 6
// 151.851 us; speedup vs baseline: 1.3534x; 1.3534x over previous
//
#include <hip/hip_runtime.h>

#define B_ 2048
#define N_ 200
#define D_ 128
#define NE1 4   // NE+1
#define NN1 3   // NN+1

// ---------------------------------------------------------------------------
// Mask storage detection (bool-bytes vs int32). Flag -> ws[0].
// ---------------------------------------------------------------------------
__global__ void detect_mask_kernel(const unsigned int* __restrict__ mw,
                                   int nwords, unsigned int* __restrict__ flag) {
  __shared__ int sbad;
  if (threadIdx.x == 0) sbad = 0;
  __syncthreads();
  int bad = 0;
  for (int i = blockIdx.x * blockDim.x + threadIdx.x; i < nwords;
       i += gridDim.x * blockDim.x)
    if (mw[i] > 1u) bad = 1;
  if (bad) sbad = 1;
  __syncthreads();
  if (threadIdx.x == 0 && sbad) atomicOr(flag, 1u);
}

// ---------------------------------------------------------------------------
// Fused kernel: TWO batch elements per block. ~32 KB LDS, VGPR cap 128.
// ---------------------------------------------------------------------------
__global__ __launch_bounds__(256, 4) void fused_mha_kernel(
    const float* __restrict__ q, const float* __restrict__ k,
    const float* __restrict__ v, const float* __restrict__ Wq,
    const float* __restrict__ Wk, const float* __restrict__ Wv,
    const float* __restrict__ rel_pri, const float* __restrict__ W_fc,
    const float* __restrict__ b_fc, const float* __restrict__ ln_gamma,
    const float* __restrict__ ln_beta, const int* __restrict__ etype,
    const int* __restrict__ utype, const void* __restrict__ maskp,
    const unsigned int* __restrict__ flag, float* __restrict__ y_out,
    float* __restrict__ attn_out) {
  const int b0 = blockIdx.x * 2;
  const int tid = threadIdx.x;
  const int g = tid & 3, grp = tid >> 2;   // 4-lane groups
  const int w = tid >> 6, l = tid & 63;    // wave / lane

  __shared__ __align__(16) float q_s[2][128];
  __shared__ __align__(16) float Qe_s[2][4][132];
  __shared__ __align__(16) float ehbuf[2][16][132];  // qM; later s[h][e][:]
  __shared__ __align__(16) float p_s[2][4][200];     // logits->probs; FC stage
  __shared__ int et_s[2][200];                       // etype | (mask<<4)
  __shared__ unsigned short perm_s[2][200];
  __shared__ int cnt_s[2][4];
  __shared__ int goff_s[2][5];
  __shared__ float pri_s[2][16];
  __shared__ float part_s[2][128];
  __shared__ float red_s[2][8];
  __shared__ int u_s[2];

  // ---------------- Phase 0: metadata for both b ----------------
  if (tid < 2) u_s[tid] = utype[b0 + tid];
  {
    int bb = tid >> 7, j = tid & 127;
    q_s[bb][j] = q[(size_t)(b0 + bb) * D_ + j];
  }
  const unsigned int isBool = flag[0];
  for (int i = tid; i < 2 * N_; i += 256) {
    int bb = (i >= N_), n = i - bb * N_;
    int e = etype[(size_t)(b0 + bb) * N_ + n];
    int m;
    if (isBool)
      m = ((const unsigned char*)maskp)[(size_t)(b0 + bb) * N_ + n];
    else
      m = ((const int*)maskp)[(size_t)(b0 + bb) * N_ + n];
    et_s[bb][n] = e | (m ? 16 : 0);
  }
  __syncthreads();

  if (tid < 32) {
    int bb = tid >> 4, e = (tid >> 2) & 3, h = tid & 3;
    pri_s[bb][e * 4 + h] =
        rel_pri[(h * NN1 + u_s[bb]) * NE1 + e] * 0.17677669529663687f;
  }

  // ---- perm count (wave w counts group w; masked -> group 4, dropped) ----
#pragma unroll
  for (int bb = 0; bb < 2; ++bb) {
    int cnt = 0;
    for (int n0 = 0; n0 < 256; n0 += 64) {
      int n = n0 + l;
      bool act = false;
      if (n < N_) {
        int em = et_s[bb][n];
        act = !(em & 16) && ((em & 3) == w);
      }
      unsigned long long m = __ballot(act);
      cnt += __popcll(m);
    }
    if (l == 0) cnt_s[bb][w] = cnt;
  }

  // ---------------- Phase 1: Qe[bb][e][j], Wq loads shared ----------------
  {
    const float4* qv0 = (const float4*)&q_s[0][0];
    const float4* qv1 = (const float4*)&q_s[1][0];
#pragma unroll
    for (int pass = 0; pass < 8; ++pass) {
      int idx = pass * 64 + grp;
      int e = idx >> 7, j = idx & 127;
      const float4* wr = (const float4*)(Wq + (size_t)(e * 128 + j) * 128);
      float acc0 = 0.f, acc1 = 0.f;
#pragma unroll
      for (int half = 0; half < 2; ++half) {
        float4 wb[4];
#pragma unroll
        for (int t = 0; t < 4; ++t) wb[t] = wr[g + 4 * (half * 4 + t)];
#pragma unroll
        for (int t = 0; t < 4; ++t) {
          int c = g + 4 * (half * 4 + t);
          float4 q0 = qv0[c];
          acc0 += wb[t].x * q0.x + wb[t].y * q0.y + wb[t].z * q0.z +
                  wb[t].w * q0.w;
          float4 q1 = qv1[c];
          acc1 += wb[t].x * q1.x + wb[t].y * q1.y + wb[t].z * q1.z +
                  wb[t].w * q1.w;
        }
      }
      acc0 += __shfl_xor(acc0, 1);
      acc0 += __shfl_xor(acc0, 2);
      acc1 += __shfl_xor(acc1, 1);
      acc1 += __shfl_xor(acc1, 2);
      if (g == 0) {
        Qe_s[0][e][j] = acc0;
        Qe_s[1][e][j] = acc1;
      }
    }
  }
  __syncthreads();

  // prefix for group offsets
  if (tid < 2) {
    int s = 0;
#pragma unroll
    for (int e = 0; e < 4; ++e) {
      goff_s[tid][e] = s;
      s += cnt_s[tid][e];
    }
    goff_s[tid][4] = s;
  }

  // ---- Phase 2: qM[bb][eh][d], Wk loads shared ----
  for (int idx = tid; idx < 16 * 128; idx += 256) {
    int eh = idx >> 7, d = idx & 127;
    int e = eh >> 2, h = eh & 3;
    const float* wkb = Wk + ((size_t)(e * 128 + h * 32)) * 128 + d;
    float acc0 = 0.f, acc1 = 0.f;
#pragma unroll
    for (int i4 = 0; i4 < 8; ++i4) {
      float w0 = wkb[(i4 * 4 + 0) * 128], w1 = wkb[(i4 * 4 + 1) * 128];
      float w2 = wkb[(i4 * 4 + 2) * 128], w3 = wkb[(i4 * 4 + 3) * 128];
      float4 qe0 = ((const float4*)&Qe_s[0][e][0])[h * 8 + i4];
      acc0 = fmaf(qe0.x, w0, acc0);
      acc0 = fmaf(qe0.y, w1, acc0);
      acc0 = fmaf(qe0.z, w2, acc0);
      acc0 = fmaf(qe0.w, w3, acc0);
      float4 qe1 = ((const float4*)&Qe_s[1][e][0])[h * 8 + i4];
      acc1 = fmaf(qe1.x, w0, acc1);
      acc1 = fmaf(qe1.y, w1, acc1);
      acc1 = fmaf(qe1.z, w2, acc1);
      acc1 = fmaf(qe1.w, w3, acc1);
    }
    ehbuf[0][eh][d] = acc0 * pri_s[0][eh];
    ehbuf[1][eh][d] = acc1 * pri_s[1][eh];
  }
  __syncthreads();

  // ---- perm fill (deterministic ballot order) ----
#pragma unroll
  for (int bb = 0; bb < 2; ++bb) {
    int base = goff_s[bb][w];
    for (int n0 = 0; n0 < 256; n0 += 64) {
      int n = n0 + l;
      bool act = false;
      if (n < N_) {
        int em = et_s[bb][n];
        act = !(em & 16) && ((em & 3) == w);
      }
      unsigned long long m = __ballot(act);
      if (act)
        perm_s[bb][base + __popcll(m & ((1ull << l) - 1ull))] =
            (unsigned short)n;
      base += __popcll(m);
    }
  }

  // ---------------- Phase 3: logits (4 lanes per n; masked skip) ----------------
#pragma unroll
  for (int pass = 0; pass < 4; ++pass) {
    int n = pass * 64 + grp;
    if (n < N_) {
#pragma unroll
      for (int bb = 0; bb < 2; ++bb) {
        int em = et_s[bb][n];
        if (em & 16) {
          if (g == 0) {
            p_s[bb][0][n] = -1e10f;
            p_s[bb][1][n] = -1e10f;
            p_s[bb][2][n] = -1e10f;
            p_s[bb][3][n] = -1e10f;
          }
        } else {
          const float4* kr =
              (const float4*)(k + ((size_t)(b0 + bb) * N_ + n) * D_);
          const int eh0 = (em & 3) * 4;
          const float4* m0 = (const float4*)&ehbuf[bb][eh0 + 0][0];
          const float4* m1 = (const float4*)&ehbuf[bb][eh0 + 1][0];
          const float4* m2 = (const float4*)&ehbuf[bb][eh0 + 2][0];
          const float4* m3 = (const float4*)&ehbuf[bb][eh0 + 3][0];
          float a0 = 0.f, a1 = 0.f, a2 = 0.f, a3 = 0.f;
#pragma unroll
          for (int half = 0; half < 2; ++half) {
            float4 kb[4];
#pragma unroll
            for (int t = 0; t < 4; ++t) kb[t] = kr[g + 4 * (half * 4 + t)];
#pragma unroll
            for (int t = 0; t < 4; ++t) {
              int c = g + 4 * (half * 4 + t);
              float4 x0 = m0[c];
              a0 += kb[t].x * x0.x + kb[t].y * x0.y + kb[t].z * x0.z +
                    kb[t].w * x0.w;
              float4 x1 = m1[c];
              a1 += kb[t].x * x1.x + kb[t].y * x1.y + kb[t].z * x1.z +
                    kb[t].w * x1.w;
              float4 x2 = m2[c];
              a2 += kb[t].x * x2.x + kb[t].y * x2.y + kb[t].z * x2.z +
                    kb[t].w * x2.w;
              float4 x3 = m3[c];
              a3 += kb[t].x * x3.x + kb[t].y * x3.y + kb[t].z * x3.z +
                    kb[t].w * x3.w;
            }
          }
          a0 += __shfl_xor(a0, 1);
          a0 += __shfl_xor(a0, 2);
          a1 += __shfl_xor(a1, 1);
          a1 += __shfl_xor(a1, 2);
          a2 += __shfl_xor(a2, 1);
          a2 += __shfl_xor(a2, 2);
          a3 += __shfl_xor(a3, 1);
          a3 += __shfl_xor(a3, 2);
          if (g == 0) {
            p_s[bb][0][n] = a0;
            p_s[bb][1][n] = a1;
            p_s[bb][2][n] = a2;
            p_s[bb][3][n] = a3;
          }
        }
      }
    }
  }
  __syncthreads();

  // ---------------- Phase 4: softmax (wave = head) + attn write ----------------
#pragma unroll
  for (int bb = 0; bb < 2; ++bb) {
    float mx = -1e30f;
    for (int n = l; n < N_; n += 64) mx = fmaxf(mx, p_s[bb][w][n]);
#pragma unroll
    for (int o = 32; o; o >>= 1) mx = fmaxf(mx, __shfl_xor(mx, o));
    float sum = 0.f;
    for (int n = l; n < N_; n += 64) {
      float e = __expf(p_s[bb][w][n] - mx);
      p_s[bb][w][n] = e;
      sum += e;
    }
#pragma unroll
    for (int o = 32; o; o >>= 1) sum += __shfl_xor(sum, o);
    float inv = 1.f / sum;
    for (int n = l; n < N_; n += 64) {
      float pp = p_s[bb][w][n] * inv;
      p_s[bb][w][n] = pp;
      attn_out[((size_t)w * B_ + (b0 + bb)) * N_ + n] = pp;
    }
  }
  __syncthreads();

  // ---------------- Phase 5: PV over etype-partitioned n ----------------
#pragma unroll
  for (int bb = 0; bb < 2; ++bb) {
    const float2* vb2 = (const float2*)(v + (size_t)(b0 + bb) * N_ * D_);
#pragma unroll
    for (int e = 0; e < 4; ++e) {
      float a0 = 0.f, a1 = 0.f;
      const int j0 = goff_s[bb][e], j1 = goff_s[bb][e + 1];
      for (int j = j0; j < j1; j += 4) {
        int nn[4];
        float pv[4];
        float2 vv[4];
#pragma unroll
        for (int u = 0; u < 4; ++u) {
          bool ok = (j + u) < j1;
          nn[u] = ok ? (int)perm_s[bb][j + u] : (int)perm_s[bb][j0];
          pv[u] = ok ? 1.f : 0.f;
        }
#pragma unroll
        for (int u = 0; u < 4; ++u) vv[u] = vb2[nn[u] * 64 + l];
#pragma unroll
        for (int u = 0; u < 4; ++u) pv[u] *= p_s[bb][w][nn[u]];
#pragma unroll
        for (int u = 0; u < 4; ++u) {
          a0 = fmaf(pv[u], vv[u].x, a0);
          a1 = fmaf(pv[u], vv[u].y, a1);
        }
      }
      ((float2*)&ehbuf[bb][e * 4 + w][0])[l] = make_float2(a0, a1);
    }
  }
  __syncthreads();

  // ---------------- Phase 6: Wv contract, loads shared across bb ----------------
#pragma unroll
  for (int pass = 0; pass < 2; ++pass) {
    int row = pass * 64 + grp;
    int hh = row >> 5;
    float acc0 = 0.f, acc1 = 0.f;
#pragma unroll
    for (int e = 0; e < 4; ++e) {
      const float4* wr = (const float4*)(Wv + ((size_t)e * 128 + row) * 128);
      const float4* s0 = (const float4*)&ehbuf[0][e * 4 + hh][0];
      const float4* s1 = (const float4*)&ehbuf[1][e * 4 + hh][0];
#pragma unroll
      for (int half = 0; half < 2; ++half) {
        float4 wb[4];
#pragma unroll
        for (int t = 0; t < 4; ++t) wb[t] = wr[g + 4 * (half * 4 + t)];
#pragma unroll
        for (int t = 0; t < 4; ++t) {
          int c = g + 4 * (half * 4 + t);
          float4 sv0 = s0[c];
          acc0 += wb[t].x * sv0.x + wb[t].y * sv0.y + wb[t].z * sv0.z +
                  wb[t].w * sv0.w;
          float4 sv1 = s1[c];
          acc1 += wb[t].x * sv1.x + wb[t].y * sv1.y + wb[t].z * sv1.z +
                  wb[t].w * sv1.w;
        }
      }
    }
    acc0 += __shfl_xor(acc0, 1);
    acc0 += __shfl_xor(acc0, 2);
    acc1 += __shfl_xor(acc1, 1);
    acc1 += __shfl_xor(acc1, 2);
    if (g == 0) {
      part_s[0][row] = acc0;
      part_s[1][row] = acc1;
    }
  }
  __syncthreads();

  // ---------------- Phase 7: FC (r-split, per bb) ----------------
#pragma unroll
  for (int bb = 0; bb < 2; ++bb) {
    const int j = tid & 127, halfR = tid >> 7;
    const float* wf = W_fc + ((size_t)u_s[bb] * 128 + halfR * 64) * 128 + j;
    float acc = 0.f;
    for (int r0 = 0; r0 < 64; r0 += 8) {
      float wv[8], ov[8];
#pragma unroll
      for (int u = 0; u < 8; ++u) wv[u] = wf[(r0 + u) * 128];
#pragma unroll
      for (int u = 0; u < 8; ++u) ov[u] = part_s[bb][halfR * 64 + r0 + u];
#pragma unroll
      for (int u = 0; u < 8; ++u) acc = fmaf(ov[u], wv[u], acc);
    }
    ((float*)&p_s[bb][0][0])[tid] = acc;
  }
  __syncthreads();

  // ---------------- Phase 8: residual + LN (both b in parallel) ----------------
  {
    const int bb = tid >> 7, j = tid & 127;
    const float* st = (const float*)&p_s[bb][0][0];
    float x = st[j] + st[128 + j] + b_fc[u_s[bb] * 128 + j] + q_s[bb][j];
    float s1 = x, s2 = x * x;
#pragma unroll
    for (int o = 32; o; o >>= 1) {
      s1 += __shfl_xor(s1, o);
      s2 += __shfl_xor(s2, o);
    }
    if ((j & 63) == 0) {
      red_s[bb][j >> 6] = s1;
      red_s[bb][4 + (j >> 6)] = s2;
    }
    __syncthreads();
    float t1 = red_s[bb][0] + red_s[bb][1];
    float t2 = red_s[bb][4] + red_s[bb][5];
    float mu = t1 * (1.f / 128.f);
    float var = t2 * (1.f / 128.f) - mu * mu;
    float yv = (x - mu) * rsqrtf(var + 1e-5f) * ln_gamma[j] + ln_beta[j];
    y_out[(size_t)(b0 + bb) * 128 + j] = yv;
  }
}

extern "C" void kernel_launch(void* const* d_in, const int* in_sizes, int n_in,
                              void* d_out, int out_size, void* d_ws,
                              size_t ws_size, hipStream_t stream) {
  const float* q = (const float*)d_in[0];
  const float* k = (const float*)d_in[1];
  const float* v = (const float*)d_in[2];
  const float* Wq = (const float*)d_in[3];
  const float* Wk = (const float*)d_in[4];
  const float* Wv = (const float*)d_in[5];
  const float* rp = (const float*)d_in[6];
  const float* Wf = (const float*)d_in[7];
  const float* bf = (const float*)d_in[8];
  const float* g = (const float*)d_in[9];
  const float* be = (const float*)d_in[10];
  const int* et = (const int*)d_in[11];
  const int* ut = (const int*)d_in[12];
  const void* mask = d_in[13];

  float* y = (float*)d_out;
  float* attn = y + (size_t)B_ * D_;
  unsigned int* flag = (unsigned int*)d_ws;

  hipMemsetAsync(d_ws, 0, 4, stream);
  detect_mask_kernel<<<64, 256, 0, stream>>>((const unsigned int*)mask,
                                             B_ * N_ / 4, flag);
  fused_mha_kernel<<<B_ / 2, 256, 0, stream>>>(q, k, v, Wq, Wk, Wv, rp, Wf, bf,
                                               g, be, et, ut, mask, flag, y,
                                               attn);
}

// Round 7
// 131.458 us; speedup vs baseline: 1.5633x; 1.1551x over previous
//
#include <hip/hip_runtime.h>

#define B_ 2048
#define N_ 200
#define D_ 128
#define NE1 4   // NE+1
#define NN1 3   // NN+1

// ---------------------------------------------------------------------------
// Mask storage detection (bool-bytes vs int32). Flag -> ws[0].
// ---------------------------------------------------------------------------
__global__ void detect_mask_kernel(const unsigned int* __restrict__ mw,
                                   int nwords, unsigned int* __restrict__ flag) {
  __shared__ int sbad;
  if (threadIdx.x == 0) sbad = 0;
  __syncthreads();
  int bad = 0;
  for (int i = blockIdx.x * blockDim.x + threadIdx.x; i < nwords;
       i += gridDim.x * blockDim.x)
    if (mw[i] > 1u) bad = 1;
  if (bad) sbad = 1;
  __syncthreads();
  if (threadIdx.x == 0 && sbad) atomicOr(flag, 1u);
}

// ---------------------------------------------------------------------------
// Fused kernel: FOUR batch elements per block, 512 threads. ~57 KB LDS.
// ---------------------------------------------------------------------------
__global__ __launch_bounds__(512, 2) void fused_mha_kernel(
    const float* __restrict__ q, const float* __restrict__ k,
    const float* __restrict__ v, const float* __restrict__ Wq,
    const float* __restrict__ Wk, const float* __restrict__ Wv,
    const float* __restrict__ rel_pri, const float* __restrict__ W_fc,
    const float* __restrict__ b_fc, const float* __restrict__ ln_gamma,
    const float* __restrict__ ln_beta, const int* __restrict__ etype,
    const int* __restrict__ utype, const void* __restrict__ maskp,
    const unsigned int* __restrict__ flag, float* __restrict__ y_out,
    float* __restrict__ attn_out) {
  const int b0 = blockIdx.x * 4;
  const int tid = threadIdx.x;
  const int g = tid & 3, grp = tid >> 2;   // 128 4-lane groups
  const int w = tid >> 6, l = tid & 63;    // 8 waves

  __shared__ __align__(16) float q_s[4][128];
  __shared__ __align__(16) float ehbuf[4][16][136];  // qM; later s[h][e][:]
  __shared__ __align__(16) float p_s[4][4][200];     // Qe overlay; logits->probs
  __shared__ int et_s[4][200];                       // etype | (mask<<4)
  __shared__ unsigned short perm_s[4][200];
  __shared__ int cnt_s[4][4];
  __shared__ int goff_s[4][5];
  __shared__ float pri_s[4][16];
  __shared__ float part_s[4][128];
  __shared__ float red_s[4][8];
  __shared__ int u_s[4];

  float* QeF = &p_s[0][0][0];  // [bb*4+e][j], stride 136 (16B-aligned rows)

  // ---------------- Phase 0: metadata for 4 b ----------------
  if (tid < 4) u_s[tid] = utype[b0 + tid];
  {
    int bb = tid >> 7, j = tid & 127;
    q_s[bb][j] = q[(size_t)(b0 + bb) * D_ + j];
  }
  const unsigned int isBool = flag[0];
  for (int i = tid; i < 4 * N_; i += 512) {
    int bb = i / 200, n = i - bb * 200;
    int e = etype[(size_t)(b0 + bb) * N_ + n];
    int m;
    if (isBool)
      m = ((const unsigned char*)maskp)[(size_t)(b0 + bb) * N_ + n];
    else
      m = ((const int*)maskp)[(size_t)(b0 + bb) * N_ + n];
    et_s[bb][n] = e | (m ? 16 : 0);
  }
  __syncthreads();

  if (tid < 64) {
    int bb = tid >> 4, e = (tid >> 2) & 3, h = tid & 3;
    pri_s[bb][e * 4 + h] =
        rel_pri[(h * NN1 + u_s[bb]) * NE1 + e] * 0.17677669529663687f;
  }

  // ---- perm count: wave w handles tasks t=2w,2w+1; t=(bb,e) ----
#pragma unroll
  for (int it = 0; it < 2; ++it) {
    int t = w * 2 + it, bb = t >> 2, e = t & 3;
    int cnt = 0;
    for (int n0 = 0; n0 < 256; n0 += 64) {
      int n = n0 + l;
      bool act = false;
      if (n < N_) {
        int em = et_s[bb][n];
        act = !(em & 16) && ((em & 3) == e);
      }
      unsigned long long m = __ballot(act);
      cnt += __popcll(m);
    }
    if (l == 0) cnt_s[bb][e] = cnt;
  }

  // ---------------- Phase 1: Qe[bb][e][j], Wq loads shared x4 ----------------
  {
#pragma unroll
    for (int pass = 0; pass < 4; ++pass) {
      int idx = pass * 128 + grp;  // 0..511
      int e = idx >> 7, j = idx & 127;
      const float4* wr = (const float4*)(Wq + (size_t)(e * 128 + j) * 128);
      float acc[4] = {0.f, 0.f, 0.f, 0.f};
#pragma unroll
      for (int half = 0; half < 2; ++half) {
        float4 wb[4];
#pragma unroll
        for (int t = 0; t < 4; ++t) wb[t] = wr[g + 4 * (half * 4 + t)];
#pragma unroll
        for (int t = 0; t < 4; ++t) {
          int c = g + 4 * (half * 4 + t);
#pragma unroll
          for (int bb = 0; bb < 4; ++bb) {
            float4 qq = ((const float4*)&q_s[bb][0])[c];
            acc[bb] += wb[t].x * qq.x + wb[t].y * qq.y + wb[t].z * qq.z +
                       wb[t].w * qq.w;
          }
        }
      }
#pragma unroll
      for (int bb = 0; bb < 4; ++bb) {
        acc[bb] += __shfl_xor(acc[bb], 1);
        acc[bb] += __shfl_xor(acc[bb], 2);
      }
      if (g == 0) {
#pragma unroll
        for (int bb = 0; bb < 4; ++bb) QeF[(bb * 4 + e) * 136 + j] = acc[bb];
      }
    }
  }
  __syncthreads();

  // prefix for group offsets
  if (tid < 4) {
    int s = 0;
#pragma unroll
    for (int e = 0; e < 4; ++e) {
      goff_s[tid][e] = s;
      s += cnt_s[tid][e];
    }
    goff_s[tid][4] = s;
  }

  // ---- Phase 2: qM[bb][eh][d], Wk column loads shared x4 ----
  for (int idx = tid; idx < 16 * 128; idx += 512) {
    int eh = idx >> 7, d = idx & 127;
    int e = eh >> 2, h = eh & 3;
    const float* wkb = Wk + ((size_t)(e * 128 + h * 32)) * 128 + d;
    float acc[4] = {0.f, 0.f, 0.f, 0.f};
#pragma unroll
    for (int i4 = 0; i4 < 8; ++i4) {
      float w0 = wkb[(i4 * 4 + 0) * 128], w1 = wkb[(i4 * 4 + 1) * 128];
      float w2 = wkb[(i4 * 4 + 2) * 128], w3 = wkb[(i4 * 4 + 3) * 128];
#pragma unroll
      for (int bb = 0; bb < 4; ++bb) {
        float4 qe = ((const float4*)(QeF + (bb * 4 + e) * 136))[h * 8 + i4];
        acc[bb] = fmaf(qe.x, w0, acc[bb]);
        acc[bb] = fmaf(qe.y, w1, acc[bb]);
        acc[bb] = fmaf(qe.z, w2, acc[bb]);
        acc[bb] = fmaf(qe.w, w3, acc[bb]);
      }
    }
#pragma unroll
    for (int bb = 0; bb < 4; ++bb)
      ehbuf[bb][eh][d] = acc[bb] * pri_s[bb][eh];
  }
  __syncthreads();

  // ---- perm fill (deterministic ballot order), overlaps phase 3 ----
#pragma unroll
  for (int it = 0; it < 2; ++it) {
    int t = w * 2 + it, bb = t >> 2, e = t & 3;
    int base = goff_s[bb][e];
    for (int n0 = 0; n0 < 256; n0 += 64) {
      int n = n0 + l;
      bool act = false;
      if (n < N_) {
        int em = et_s[bb][n];
        act = !(em & 16) && ((em & 3) == e);
      }
      unsigned long long m = __ballot(act);
      if (act)
        perm_s[bb][base + __popcll(m & ((1ull << l) - 1ull))] =
            (unsigned short)n;
      base += __popcll(m);
    }
  }

  // ---------------- Phase 3: logits; task id=(bb,n), masked skip ----------------
  for (int pass = 0; pass < 7; ++pass) {
    int id = pass * 128 + grp;
    if (id < 4 * N_) {
      int bb = id / 200, n = id - bb * 200;
      int em = et_s[bb][n];
      if (em & 16) {
        if (g == 0) {
          p_s[bb][0][n] = -1e10f;
          p_s[bb][1][n] = -1e10f;
          p_s[bb][2][n] = -1e10f;
          p_s[bb][3][n] = -1e10f;
        }
      } else {
        const float4* kr =
            (const float4*)(k + ((size_t)(b0 + bb) * N_ + n) * D_);
        const int eh0 = (em & 3) * 4;
        const float4* m0 = (const float4*)&ehbuf[bb][eh0 + 0][0];
        const float4* m1 = (const float4*)&ehbuf[bb][eh0 + 1][0];
        const float4* m2 = (const float4*)&ehbuf[bb][eh0 + 2][0];
        const float4* m3 = (const float4*)&ehbuf[bb][eh0 + 3][0];
        float a0 = 0.f, a1 = 0.f, a2 = 0.f, a3 = 0.f;
#pragma unroll
        for (int half = 0; half < 2; ++half) {
          float4 kb[4];
#pragma unroll
          for (int t = 0; t < 4; ++t) kb[t] = kr[g + 4 * (half * 4 + t)];
#pragma unroll
          for (int t = 0; t < 4; ++t) {
            int c = g + 4 * (half * 4 + t);
            float4 x0 = m0[c];
            a0 += kb[t].x * x0.x + kb[t].y * x0.y + kb[t].z * x0.z +
                  kb[t].w * x0.w;
            float4 x1 = m1[c];
            a1 += kb[t].x * x1.x + kb[t].y * x1.y + kb[t].z * x1.z +
                  kb[t].w * x1.w;
            float4 x2 = m2[c];
            a2 += kb[t].x * x2.x + kb[t].y * x2.y + kb[t].z * x2.z +
                  kb[t].w * x2.w;
            float4 x3 = m3[c];
            a3 += kb[t].x * x3.x + kb[t].y * x3.y + kb[t].z * x3.z +
                  kb[t].w * x3.w;
          }
        }
        a0 += __shfl_xor(a0, 1);
        a0 += __shfl_xor(a0, 2);
        a1 += __shfl_xor(a1, 1);
        a1 += __shfl_xor(a1, 2);
        a2 += __shfl_xor(a2, 1);
        a2 += __shfl_xor(a2, 2);
        a3 += __shfl_xor(a3, 1);
        a3 += __shfl_xor(a3, 2);
        if (g == 0) {
          p_s[bb][0][n] = a0;
          p_s[bb][1][n] = a1;
          p_s[bb][2][n] = a2;
          p_s[bb][3][n] = a3;
        }
      }
    }
  }
  __syncthreads();

  // ---------------- Phase 4: softmax; wave task t=(bb,h) ----------------
#pragma unroll
  for (int it = 0; it < 2; ++it) {
    int t = w * 2 + it, bb = t >> 2, h = t & 3;
    float mx = -1e30f;
    for (int n = l; n < N_; n += 64) mx = fmaxf(mx, p_s[bb][h][n]);
#pragma unroll
    for (int o = 32; o; o >>= 1) mx = fmaxf(mx, __shfl_xor(mx, o));
    float sum = 0.f;
    for (int n = l; n < N_; n += 64) {
      float e = __expf(p_s[bb][h][n] - mx);
      p_s[bb][h][n] = e;
      sum += e;
    }
#pragma unroll
    for (int o = 32; o; o >>= 1) sum += __shfl_xor(sum, o);
    float inv = 1.f / sum;
    for (int n = l; n < N_; n += 64) {
      float pp = p_s[bb][h][n] * inv;
      p_s[bb][h][n] = pp;
      attn_out[((size_t)h * B_ + (b0 + bb)) * N_ + n] = pp;
    }
  }
  // no barrier needed: PV task mapping == softmax task mapping (same wave)

  // ---------------- Phase 5: PV over etype-partitioned n ----------------
#pragma unroll
  for (int it = 0; it < 2; ++it) {
    int t = w * 2 + it, bb = t >> 2, h = t & 3;
    const float2* vb2 = (const float2*)(v + (size_t)(b0 + bb) * N_ * D_);
#pragma unroll
    for (int e = 0; e < 4; ++e) {
      float a0 = 0.f, a1 = 0.f;
      const int j0 = goff_s[bb][e], j1 = goff_s[bb][e + 1];
      for (int j = j0; j < j1; j += 4) {
        int nn[4];
        float pv[4];
        float2 vv[4];
#pragma unroll
        for (int u = 0; u < 4; ++u) {
          bool ok = (j + u) < j1;
          nn[u] = ok ? (int)perm_s[bb][j + u] : (int)perm_s[bb][j0];
          pv[u] = ok ? 1.f : 0.f;
        }
#pragma unroll
        for (int u = 0; u < 4; ++u) vv[u] = vb2[nn[u] * 64 + l];
#pragma unroll
        for (int u = 0; u < 4; ++u) pv[u] *= p_s[bb][h][nn[u]];
#pragma unroll
        for (int u = 0; u < 4; ++u) {
          a0 = fmaf(pv[u], vv[u].x, a0);
          a1 = fmaf(pv[u], vv[u].y, a1);
        }
      }
      ((float2*)&ehbuf[bb][e * 4 + h][0])[l] = make_float2(a0, a1);
    }
  }
  __syncthreads();

  // ---------------- Phase 6: Wv contract; loads shared x4 ----------------
  {
    int row = grp, hh = row >> 5;
    float acc[4] = {0.f, 0.f, 0.f, 0.f};
#pragma unroll
    for (int e = 0; e < 4; ++e) {
      const float4* wr = (const float4*)(Wv + ((size_t)e * 128 + row) * 128);
#pragma unroll
      for (int half = 0; half < 2; ++half) {
        float4 wb[4];
#pragma unroll
        for (int t = 0; t < 4; ++t) wb[t] = wr[g + 4 * (half * 4 + t)];
#pragma unroll
        for (int t = 0; t < 4; ++t) {
          int c = g + 4 * (half * 4 + t);
#pragma unroll
          for (int bb = 0; bb < 4; ++bb) {
            float4 sv = ((const float4*)&ehbuf[bb][e * 4 + hh][0])[c];
            acc[bb] += wb[t].x * sv.x + wb[t].y * sv.y + wb[t].z * sv.z +
                       wb[t].w * sv.w;
          }
        }
      }
    }
#pragma unroll
    for (int bb = 0; bb < 4; ++bb) {
      acc[bb] += __shfl_xor(acc[bb], 1);
      acc[bb] += __shfl_xor(acc[bb], 2);
    }
    if (g == 0) {
#pragma unroll
      for (int bb = 0; bb < 4; ++bb) part_s[bb][row] = acc[bb];
    }
  }
  __syncthreads();

  // ---------------- Phase 7: FC (one (bb,j) per thread) + residual + LN ----------------
  {
    const int bb = tid >> 7, j = tid & 127;
    const float* wf = W_fc + ((size_t)u_s[bb] * 128) * 128 + j;
    float acc = 0.f;
    for (int r0 = 0; r0 < 128; r0 += 8) {
      float wv[8], ov[8];
#pragma unroll
      for (int u = 0; u < 8; ++u) wv[u] = wf[(r0 + u) * 128];
#pragma unroll
      for (int u = 0; u < 8; ++u) ov[u] = part_s[bb][r0 + u];
#pragma unroll
      for (int u = 0; u < 8; ++u) acc = fmaf(ov[u], wv[u], acc);
    }
    float x = acc + b_fc[u_s[bb] * 128 + j] + q_s[bb][j];

    float s1 = x, s2 = x * x;
#pragma unroll
    for (int o = 32; o; o >>= 1) {
      s1 += __shfl_xor(s1, o);
      s2 += __shfl_xor(s2, o);
    }
    const int half = (tid >> 6) & 1;
    if (l == 0) {
      red_s[bb][half] = s1;
      red_s[bb][4 + half] = s2;
    }
    __syncthreads();
    float t1 = red_s[bb][0] + red_s[bb][1];
    float t2 = red_s[bb][4] + red_s[bb][5];
    float mu = t1 * (1.f / 128.f);
    float var = t2 * (1.f / 128.f) - mu * mu;
    float yv = (x - mu) * rsqrtf(var + 1e-5f) * ln_gamma[j] + ln_beta[j];
    y_out[(size_t)(b0 + bb) * 128 + j] = yv;
  }
}

extern "C" void kernel_launch(void* const* d_in, const int* in_sizes, int n_in,
                              void* d_out, int out_size, void* d_ws,
                              size_t ws_size, hipStream_t stream) {
  const float* q = (const float*)d_in[0];
  const float* k = (const float*)d_in[1];
  const float* v = (const float*)d_in[2];
  const float* Wq = (const float*)d_in[3];
  const float* Wk = (const float*)d_in[4];
  const float* Wv = (const float*)d_in[5];
  const float* rp = (const float*)d_in[6];
  const float* Wf = (const float*)d_in[7];
  const float* bf = (const float*)d_in[8];
  const float* g = (const float*)d_in[9];
  const float* be = (const float*)d_in[10];
  const int* et = (const int*)d_in[11];
  const int* ut = (const int*)d_in[12];
  const void* mask = d_in[13];

  float* y = (float*)d_out;
  float* attn = y + (size_t)B_ * D_;
  unsigned int* flag = (unsigned int*)d_ws;

  hipMemsetAsync(d_ws, 0, 4, stream);
  detect_mask_kernel<<<64, 256, 0, stream>>>((const unsigned int*)mask,
                                             B_ * N_ / 4, flag);
  fused_mha_kernel<<<B_ / 4, 512, 0, stream>>>(q, k, v, Wq, Wk, Wv, rp, Wf, bf,
                                               g, be, et, ut, mask, flag, y,
                                               attn);
}